// Round 5
// baseline (388.952 us; speedup 1.0000x reference)
//
#include <hip/hip_runtime.h>
#include <math.h>

// clDice loss: 16 x 1 x 1024 x 1024 fp32 inputs, scalar fp32 output.
// Single fused kernel (both phases, z=0..31): erosion cascade e1..e4 +
// dilate + fast-GELU skel updates + reductions, all in LDS.
// Round 5: vectorized LDS access (b128/b64), v_min3/v_max3-shaped trees,
// 4-cells-per-thread erode, 2x4-px-per-thread updates.

#define HH 1024
#define WW 1024
#define NIMG 16
constexpr int IMG_ELEMS = HH * WW;
constexpr int TILE_W = 128;
constexpr int TILE_H = 32;
constexpr int BLKT = 512;
constexpr int FR_W = 140;             // 138 padded to multiple of 4
constexpr int FR_H = 42;
constexpr int FRAME = FR_H * FR_W;    // 5880
constexpr int NGX = FR_W / 4;         // 35 col-groups per row
constexpr int PSLOTS = 128;
constexpr int DSLOTS = 16;
constexpr int GRID_X = WW / TILE_W;   // 8
constexpr int GRID_Y = HH / TILE_H;   // 32

// ---- fast math: A&S 7.1.26 erf (|eps|<=1.5e-7) with v_exp_f32 / v_rcp_f32
__device__ __forceinline__ float gelu_fast(float x) {
    float z = x * 0.70710678118654752440f;
    float az = fabsf(z);
    float t = __builtin_amdgcn_rcpf(fmaf(az, 0.3275911f, 1.0f));
    float e = __expf(-az * az);
    float p = fmaf(1.061405429f, t, -1.453152027f);
    p = fmaf(p, t, 1.421413741f);
    p = fmaf(p, t, -0.284496736f);
    p = fmaf(p, t, 0.254829592f);
    p = p * t;
    float E = fmaf(-p, e, 1.0f);           // erf(|z|)
    float erf_s = copysignf(E, x);
    return 0.5f * x * (1.0f + erf_s);
}

__device__ __forceinline__ float sigmoid_fast(float x) {
    return __builtin_amdgcn_rcpf(1.0f + __expf(-x));
}

// ---- erode level K: 5-pt cross min, 4 cells per iteration, full padded
// width (junk cells at cols <K or >=FR_W-K are never read by valid
// consumers). Linear min chains -> v_min3 pairs.
template <int K>
__device__ __forceinline__ void erode4(const float* __restrict__ S,
                                       float* __restrict__ D, int tid) {
    constexpr int RN = FR_H - 2 * K;
    constexpr int n = RN * NGX;
    for (int i = tid; i < n; i += BLKT) {
        int r = i / NGX;              // magic-mul (const divisor)
        int g = i - r * NGX;
        int o = (K + r) * FR_W + 4 * g;
        float4 up = *(const float4*)&S[o - FR_W];
        float4 dn = *(const float4*)&S[o + FR_W];
        float4 ce = *(const float4*)&S[o];
        float lf = S[o - 1];
        float rt = S[o + 4];
        float4 res;
        res.x = fminf(fminf(fminf(fminf(up.x, dn.x), ce.x), lf),   ce.y);
        res.y = fminf(fminf(fminf(fminf(up.y, dn.y), ce.y), ce.x), ce.z);
        res.z = fminf(fminf(fminf(fminf(up.z, dn.z), ce.z), ce.y), ce.w);
        res.w = fminf(fminf(fminf(fminf(up.w, dn.w), ce.w), ce.z), rt);
        *(float4*)&D[o] = res;
    }
}

// Replicate clamped in-image values into out-of-image cells of level K's
// extent (edge blocks only). Writes only out-of-image cells, reads only
// in-image cells: no intra-pass race. Replication == +/-inf pad semantics
// for all downstream min/max consumers.
template <int K>
__device__ __forceinline__ void fixup(float* __restrict__ D, int tid,
                                      int y0, int x0) {
    constexpr int RN = FR_H - 2 * K;
    constexpr int n = RN * FR_W;
    for (int i = tid; i < n; i += BLKT) {
        int r = i / FR_W;
        int c = i - r * FR_W;
        int ly = K + r;
        int gy = y0 - 5 + ly, gx = x0 - 5 + c;
        if (gy < 0 || gy >= HH || gx < 0 || gx >= WW) {
            int cly = min(max(gy, 0), HH - 1) - (y0 - 5);
            int clx = min(max(gx, 0), WW - 1) - (x0 - 5);
            D[ly * FR_W + c] = D[cly * FR_W + clx];
        }
    }
}

// One dilate+GELU update level. Thread owns 2 rows x 4 cols.
// UPD 0: skel = gelu(prev - dil); load oth; (+dice sums if ph1)
// UPD 1: skel += gelu(delta - skel*delta)
// UPD 2: final: accumulate a0 += s, a1 += s*oth (no skel write-back needed)
template <int UPD>
__device__ __forceinline__ void do_update(
        const float* __restrict__ P, const float* __restrict__ C,
        int rg, int cg, float (&skel)[8], float (&oth)[8],
        const float* __restrict__ OT, size_t base, int x0, int y0, bool ph1,
        float& d0, float& d1, float& d2, float& a0, float& a1) {
    const int wbase = (4 + 2 * rg) * FR_W + (4 + 4 * cg);
    float w[4][6];
#pragma unroll
    for (int j = 0; j < 4; j++) {
        float4 a = *(const float4*)&C[wbase + j * FR_W];
        float2 b = *(const float2*)&C[wbase + j * FR_W + 4];
        w[j][0] = a.x; w[j][1] = a.y; w[j][2] = a.z;
        w[j][3] = a.w; w[j][4] = b.x; w[j][5] = b.y;
    }
    // row max3 (v_max3), then vertical max3 for the two output rows
    float rm[4][4];
#pragma unroll
    for (int j = 0; j < 4; j++) {
#pragma unroll
        for (int i = 0; i < 4; i++)
            rm[j][i] = fmaxf(fmaxf(w[j][i], w[j][i + 1]), w[j][i + 2]);
    }
    float dil[2][4];
#pragma unroll
    for (int i = 0; i < 4; i++) {
        dil[0][i] = fmaxf(fmaxf(rm[0][i], rm[1][i]), rm[2][i]);
        dil[1][i] = fmaxf(fmaxf(rm[1][i], rm[2][i]), rm[3][i]);
    }
    // prev values: rows 5+2rg..6+2rg, cols 5+4cg..8+4cg
    const int pbase = (5 + 2 * rg) * FR_W + (4 + 4 * cg);
    float pr[2][4];
#pragma unroll
    for (int j = 0; j < 2; j++) {
        float4 a = *(const float4*)&P[pbase + j * FR_W];
        float e  = P[pbase + j * FR_W + 4];
        pr[j][0] = a.y; pr[j][1] = a.z; pr[j][2] = a.w; pr[j][3] = e;
    }
#pragma unroll
    for (int j = 0; j < 2; j++) {
        float4 t4;
        if (UPD == 0)
            t4 = *(const float4*)&OT[base + (size_t)(y0 + 2 * rg + j) * WW
                                     + (x0 + 4 * cg)];
#pragma unroll
        for (int i = 0; i < 4; i++) {
            int k = j * 4 + i;
            float prev = pr[j][i];
            float delta = gelu_fast(prev - dil[j][i]);
            if (UPD == 0) {
                skel[k] = delta;
                float t = (i == 0) ? t4.x : (i == 1) ? t4.y : (i == 2) ? t4.z : t4.w;
                oth[k] = t;
                if (ph1) {
                    float pv = sigmoid_fast(prev);
                    d0 += pv * t; d1 += pv; d2 += t;
                }
            } else if (UPD == 1) {
                skel[k] += gelu_fast(delta - skel[k] * delta);
            } else {
                float s = skel[k] + gelu_fast(delta - skel[k] * delta);
                a0 += s;
                a1 += s * oth[k];
            }
        }
    }
}

// accP: PSLOTS cachelines of 32 floats: slot*32 + {0:sumP,1:sumP*t,2:sumT,3:sumT*p}
// accD: (img*DSLOTS + s)*32 + {0:inter, 1:sum sigmoid(p), 2:sum t}
__global__ __launch_bounds__(BLKT) void cl_fused(
        const float* __restrict__ y_pred,
        const float* __restrict__ y_true,
        float* __restrict__ accP,
        float* __restrict__ accD) {
    __shared__ __align__(16) float Abuf[FRAME + 8];
    __shared__ __align__(16) float Bbuf[FRAME + 8];
    __shared__ float sh[40];
    float* A = Abuf + 4;   // +/-4-float pad catches o-1 / o+4 spills
    float* B = Bbuf + 4;

    const int x0 = blockIdx.x * TILE_W;
    const int y0 = blockIdx.y * TILE_H;
    const bool PH1 = blockIdx.z < NIMG;
    const int img = blockIdx.z & (NIMG - 1);
    const float* __restrict__ X  = PH1 ? y_pred : y_true;
    const float* __restrict__ OT = PH1 ? y_true : y_pred;
    const size_t base = (size_t)img * IMG_ELEMS;
    const int tid = threadIdx.x;
    const bool edge = (x0 == 0) || (y0 == 0) ||
                      (x0 + TILE_W == WW) || (y0 + TILE_H == HH);

    const int cg = tid & 31;        // col group: tile cols 4cg..4cg+3
    const int rg = tid >> 5;        // row group: tile rows 2rg..2rg+1

    // ---- load X tile + halo (clamp-to-edge), full padded width
    for (int i = tid; i < FRAME; i += BLKT) {
        int ly = i / FR_W, lx = i - ly * FR_W;
        int gy = min(max(y0 - 5 + ly, 0), HH - 1);
        int gx = min(max(x0 - 5 + lx, 0), WW - 1);
        A[i] = X[base + (size_t)gy * WW + gx];
    }
    __syncthreads();

    float skel[8], oth[8];
    float d0 = 0.f, d1 = 0.f, d2 = 0.f, a0 = 0.f, a1 = 0.f;

    erode4<1>(A, B, tid);
    __syncthreads();
    if (edge) { fixup<1>(B, tid, y0, x0); __syncthreads(); }
    do_update<0>(A, B, rg, cg, skel, oth, OT, base, x0, y0, PH1, d0, d1, d2, a0, a1);
    __syncthreads();

    erode4<2>(B, A, tid);
    __syncthreads();
    if (edge) { fixup<2>(A, tid, y0, x0); __syncthreads(); }
    do_update<1>(B, A, rg, cg, skel, oth, OT, base, x0, y0, PH1, d0, d1, d2, a0, a1);
    __syncthreads();

    erode4<3>(A, B, tid);
    __syncthreads();
    if (edge) { fixup<3>(B, tid, y0, x0); __syncthreads(); }
    do_update<1>(A, B, rg, cg, skel, oth, OT, base, x0, y0, PH1, d0, d1, d2, a0, a1);
    __syncthreads();

    erode4<4>(B, A, tid);
    __syncthreads();
    if (edge) { fixup<4>(A, tid, y0, x0); __syncthreads(); }
    do_update<2>(B, A, rg, cg, skel, oth, OT, base, x0, y0, PH1, d0, d1, d2, a0, a1);

    // ---- block reduction: wave shuffle -> LDS -> spread atomics
    int wave = tid >> 6, lane = tid & 63;
    for (int o = 32; o > 0; o >>= 1) {
        a0 += __shfl_down(a0, o, 64);
        a1 += __shfl_down(a1, o, 64);
    }
    if (lane == 0) { sh[wave] = a0; sh[8 + wave] = a1; }
    if (PH1) {
        for (int o = 32; o > 0; o >>= 1) {
            d0 += __shfl_down(d0, o, 64);
            d1 += __shfl_down(d1, o, 64);
            d2 += __shfl_down(d2, o, 64);
        }
        if (lane == 0) { sh[16 + wave] = d0; sh[24 + wave] = d1; sh[32 + wave] = d2; }
    }
    __syncthreads();
    if (tid == 0) {
        float s0 = 0.f, s1 = 0.f;
        for (int wv = 0; wv < 8; wv++) { s0 += sh[wv]; s1 += sh[8 + wv]; }
        int lb = blockIdx.x + GRID_X * blockIdx.y;
        int slot = (lb + blockIdx.z * 37) & (PSLOTS - 1);
        atomicAdd(&accP[slot * 32 + (PH1 ? 0 : 2)], s0);
        atomicAdd(&accP[slot * 32 + (PH1 ? 1 : 3)], s1);
        if (PH1) {
            float t0 = 0.f, t1 = 0.f, t2 = 0.f;
            for (int wv = 0; wv < 8; wv++) {
                t0 += sh[16 + wv]; t1 += sh[24 + wv]; t2 += sh[32 + wv];
            }
            float* dst = accD + (size_t)(img * DSLOTS + (lb & (DSLOTS - 1))) * 32;
            atomicAdd(&dst[0], t0);
            atomicAdd(&dst[1], t1);
            atomicAdd(&dst[2], t2);
        }
    }
}

__global__ __launch_bounds__(256) void final_combine(
        const float* __restrict__ accP,
        const float* __restrict__ accD,
        float* __restrict__ out) {
    __shared__ float shp[2][4];
    __shared__ float shd[NIMG][3];
    int tid = threadIdx.x;
    int lane = tid & 63, wave = tid >> 6;

    float p0 = 0.f, p1 = 0.f, p2 = 0.f, p3 = 0.f;
    if (tid < PSLOTS) {
        const float* s = accP + tid * 32;
        p0 = s[0]; p1 = s[1]; p2 = s[2]; p3 = s[3];
    }
    for (int o = 32; o > 0; o >>= 1) {
        p0 += __shfl_down(p0, o, 64); p1 += __shfl_down(p1, o, 64);
        p2 += __shfl_down(p2, o, 64); p3 += __shfl_down(p3, o, 64);
    }
    if (lane == 0 && wave < 2) {
        shp[wave][0] = p0; shp[wave][1] = p1; shp[wave][2] = p2; shp[wave][3] = p3;
    }

    int n = tid >> 4, s16 = tid & 15;
    const float* d = accD + (size_t)(n * DSLOTS + s16) * 32;
    float q0 = d[0], q1 = d[1], q2 = d[2];
    for (int o = 8; o > 0; o >>= 1) {
        q0 += __shfl_down(q0, o, 16);
        q1 += __shfl_down(q1, o, 16);
        q2 += __shfl_down(q2, o, 16);
    }
    if (s16 == 0) { shd[n][0] = q0; shd[n][1] = q1; shd[n][2] = q2; }
    __syncthreads();

    if (tid == 0) {
        float sumP  = shp[0][0] + shp[1][0];
        float sumPt = shp[0][1] + shp[1][1];
        float sumT  = shp[0][2] + shp[1][2];
        float sumTp = shp[0][3] + shp[1][3];
        const float SMOOTH = 1.0f;
        float tprec = (sumPt + SMOOTH) / (sumP + SMOOTH);
        float tsens = (sumTp + SMOOTH) / (sumT + SMOOTH);
        float cl = 1.0f - 2.0f * (tprec * tsens) / (tprec + tsens);
        const float EPS = 1e-4f;
        float dsum = 0.f;
        for (int k = 0; k < NIMG; k++) {
            float gd = (2.0f * shd[k][0] + EPS) / (shd[k][1] + shd[k][2] + EPS);
            dsum += 1.0f - gd;
        }
        out[0] = 0.5f * cl + 0.5f * (dsum / (float)NIMG);
    }
}

extern "C" void kernel_launch(void* const* d_in, const int* in_sizes, int n_in,
                              void* d_out, int out_size, void* d_ws, size_t ws_size,
                              hipStream_t stream) {
    const float* y_pred = (const float*)d_in[0];
    const float* y_true = (const float*)d_in[1];
    float* out = (float*)d_out;

    float* accP = (float*)d_ws;                  // 128*32 floats
    float* accD = accP + PSLOTS * 32;            // 16*16*32 floats

    hipMemsetAsync(accP, 0, (PSLOTS * 32 + NIMG * DSLOTS * 32) * sizeof(float),
                   stream);

    dim3 grd(GRID_X, GRID_Y, 2 * NIMG), blk(BLKT);   // 8192 blocks, both phases
    cl_fused<<<grd, blk, 0, stream>>>(y_pred, y_true, accP, accD);
    final_combine<<<1, 256, 0, stream>>>(accP, accD, out);
}

// Round 6
// 388.342 us; speedup vs baseline: 1.0016x; 1.0016x over previous
//
#include <hip/hip_runtime.h>
#include <math.h>

// clDice loss: 16 x 1 x 1024 x 1024 fp32 inputs, scalar fp32 output.
// Single fused kernel (both phases, z=0..31): erosion cascade e1..e4 +
// dilate + fast-GELU skel updates + reductions, all in LDS.
// Round 6: all LDS accesses at lane-stride <= 2 dwords (2-way bank aliasing
// is free on CDNA4); erode = 2 cells/thread via float2; update = 2 cols x
// 4 rows/thread with b64 window reads.

#define HH 1024
#define WW 1024
#define NIMG 16
constexpr int IMG_ELEMS = HH * WW;
constexpr int TILE_W = 128;
constexpr int TILE_H = 32;
constexpr int BLKT = 512;
constexpr int FR_W = 140;             // padded to multiple of 4
constexpr int FR_H = 42;
constexpr int FRAME = FR_H * FR_W;    // 5880
constexpr int PAIRS = FR_W / 2;       // 70 col-pairs per row
constexpr int PSLOTS = 128;
constexpr int DSLOTS = 16;
constexpr int GRID_X = WW / TILE_W;   // 8
constexpr int GRID_Y = HH / TILE_H;   // 32

// ---- fast math: A&S 7.1.26 erf (|eps|<=1.5e-7) with v_exp_f32 / v_rcp_f32
__device__ __forceinline__ float gelu_fast(float x) {
    float z = x * 0.70710678118654752440f;
    float az = fabsf(z);
    float t = __builtin_amdgcn_rcpf(fmaf(az, 0.3275911f, 1.0f));
    float e = __expf(-az * az);
    float p = fmaf(1.061405429f, t, -1.453152027f);
    p = fmaf(p, t, 1.421413741f);
    p = fmaf(p, t, -0.284496736f);
    p = fmaf(p, t, 0.254829592f);
    p = p * t;
    float E = fmaf(-p, e, 1.0f);           // erf(|z|)
    float erf_s = copysignf(E, x);
    return 0.5f * x * (1.0f + erf_s);
}

__device__ __forceinline__ float sigmoid_fast(float x) {
    return __builtin_amdgcn_rcpf(1.0f + __expf(-x));
}

// ---- erode level K: 5-pt cross min, 2 cells/thread via float2 (b64 at
// 8B lane stride -> 2-way aliasing, free). Junk cells outside the valid
// extent are computed but never read by valid consumers.
template <int K>
__device__ __forceinline__ void erode2(const float* __restrict__ S,
                                       float* __restrict__ D, int tid) {
    constexpr int RN = FR_H - 2 * K;
    constexpr int n = RN * PAIRS;
    for (int i = tid; i < n; i += BLKT) {
        int r = i / PAIRS;            // magic-mul (const divisor)
        int p = i - r * PAIRS;
        int o = (K + r) * FR_W + 2 * p;
        float2 up = *(const float2*)&S[o - FR_W];
        float2 dn = *(const float2*)&S[o + FR_W];
        float2 ce = *(const float2*)&S[o];
        float lf = S[o - 1];
        float rt = S[o + 2];
        float2 res;
        res.x = fminf(fminf(up.x, dn.x), fminf(ce.x, fminf(lf, ce.y)));
        res.y = fminf(fminf(up.y, dn.y), fminf(ce.y, fminf(ce.x, rt)));
        *(float2*)&D[o] = res;
    }
}

// Replicate clamped in-image values into out-of-image cells of level K's
// extent (edge blocks only). Writes only out-of-image cells, reads only
// in-image cells: no intra-pass race. Replication == +/-inf pad semantics
// for all downstream min/max consumers.
template <int K>
__device__ __forceinline__ void fixup(float* __restrict__ D, int tid,
                                      int y0, int x0) {
    constexpr int RN = FR_H - 2 * K;
    constexpr int n = RN * FR_W;
    for (int i = tid; i < n; i += BLKT) {
        int r = i / FR_W;
        int c = i - r * FR_W;
        int ly = K + r;
        int gy = y0 - 5 + ly, gx = x0 - 5 + c;
        if (gy < 0 || gy >= HH || gx < 0 || gx >= WW) {
            int cly = min(max(gy, 0), HH - 1) - (y0 - 5);
            int clx = min(max(gx, 0), WW - 1) - (x0 - 5);
            D[ly * FR_W + c] = D[cly * FR_W + clx];
        }
    }
}

// One dilate+GELU update level. Thread owns 2 cols x 4 rows (8 px).
//   cp = tid & 63  -> tile cols 2cp, 2cp+1 (frame cols 5+2cp, 6+2cp)
//   rq = tid >> 6  -> tile rows 4rq..4rq+3 (frame rows 5+4rq..8+4rq)
// UPD 0: skel = gelu(prev - dil); load oth; (+dice sums if ph1)
// UPD 1: skel += gelu(delta - skel*delta)
// UPD 2: final: a0 += s, a1 += s*oth (no write-back)
template <int UPD>
__device__ __forceinline__ void do_update(
        const float* __restrict__ P, const float* __restrict__ C,
        int rq, int cp, float (&skel)[8], float (&oth)[8],
        const float* __restrict__ OT, size_t base, int x0, int y0, bool ph1,
        float& d0, float& d1, float& d2, float& a0, float& a1) {
    const int wcol = 4 + 2 * cp;              // even dword -> aligned b64
    // window: 6 rows x 4 cols, read as 2 b64 per row (lane stride 2 dwords)
    float rm0[6], rm1[6];
#pragma unroll
    for (int j = 0; j < 6; j++) {
        const int ro = (4 + 4 * rq + j) * FR_W + wcol;
        float2 a = *(const float2*)&C[ro];
        float2 b = *(const float2*)&C[ro + 2];
        float t = fmaxf(a.y, b.x);
        rm0[j] = fmaxf(t, a.x);               // row max for out col 2cp
        rm1[j] = fmaxf(t, b.y);               // row max for out col 2cp+1
    }
#pragma unroll
    for (int j = 0; j < 4; j++) {
        float dil0 = fmaxf(fmaxf(rm0[j], rm0[j + 1]), rm0[j + 2]);
        float dil1 = fmaxf(fmaxf(rm1[j], rm1[j + 1]), rm1[j + 2]);
        const int po = (5 + 4 * rq + j) * FR_W + 5 + 2 * cp;
        float prev0 = P[po];
        float prev1 = P[po + 1];
        float delta0 = gelu_fast(prev0 - dil0);
        float delta1 = gelu_fast(prev1 - dil1);
        int k = 2 * j;
        if (UPD == 0) {
            skel[k] = delta0;
            skel[k + 1] = delta1;
            float2 t2 = *(const float2*)&OT[base
                          + (size_t)(y0 + 4 * rq + j) * WW + (x0 + 2 * cp)];
            oth[k] = t2.x;
            oth[k + 1] = t2.y;
            if (ph1) {
                float pv0 = sigmoid_fast(prev0);
                float pv1 = sigmoid_fast(prev1);
                d0 += pv0 * t2.x + pv1 * t2.y;
                d1 += pv0 + pv1;
                d2 += t2.x + t2.y;
            }
        } else if (UPD == 1) {
            skel[k]     += gelu_fast(delta0 - skel[k] * delta0);
            skel[k + 1] += gelu_fast(delta1 - skel[k + 1] * delta1);
        } else {
            float s0 = skel[k]     + gelu_fast(delta0 - skel[k] * delta0);
            float s1 = skel[k + 1] + gelu_fast(delta1 - skel[k + 1] * delta1);
            a0 += s0 + s1;
            a1 += s0 * oth[k] + s1 * oth[k + 1];
        }
    }
}

// accP: PSLOTS cachelines of 32 floats: slot*32 + {0:sumP,1:sumP*t,2:sumT,3:sumT*p}
// accD: (img*DSLOTS + s)*32 + {0:inter, 1:sum sigmoid(p), 2:sum t}
__global__ __launch_bounds__(BLKT) void cl_fused(
        const float* __restrict__ y_pred,
        const float* __restrict__ y_true,
        float* __restrict__ accP,
        float* __restrict__ accD) {
    __shared__ __align__(16) float Abuf[FRAME + 8];
    __shared__ __align__(16) float Bbuf[FRAME + 8];
    __shared__ float sh[40];
    float* A = Abuf + 4;   // +/-4-float pad catches o-1 / o+2 spills
    float* B = Bbuf + 4;

    const int x0 = blockIdx.x * TILE_W;
    const int y0 = blockIdx.y * TILE_H;
    const bool PH1 = blockIdx.z < NIMG;
    const int img = blockIdx.z & (NIMG - 1);
    const float* __restrict__ X  = PH1 ? y_pred : y_true;
    const float* __restrict__ OT = PH1 ? y_true : y_pred;
    const size_t base = (size_t)img * IMG_ELEMS;
    const int tid = threadIdx.x;
    const bool edge = (x0 == 0) || (y0 == 0) ||
                      (x0 + TILE_W == WW) || (y0 + TILE_H == HH);

    const int cp = tid & 63;        // col-pair
    const int rq = tid >> 6;        // row-quad

    // ---- load X tile + halo (clamp-to-edge), stride-1 lanes (conflict-free)
    for (int i = tid; i < FRAME; i += BLKT) {
        int ly = i / FR_W, lx = i - ly * FR_W;
        int gy = min(max(y0 - 5 + ly, 0), HH - 1);
        int gx = min(max(x0 - 5 + lx, 0), WW - 1);
        A[i] = X[base + (size_t)gy * WW + gx];
    }
    __syncthreads();

    float skel[8], oth[8];
    float d0 = 0.f, d1 = 0.f, d2 = 0.f, a0 = 0.f, a1 = 0.f;

    erode2<1>(A, B, tid);
    __syncthreads();
    if (edge) { fixup<1>(B, tid, y0, x0); __syncthreads(); }
    do_update<0>(A, B, rq, cp, skel, oth, OT, base, x0, y0, PH1, d0, d1, d2, a0, a1);
    __syncthreads();

    erode2<2>(B, A, tid);
    __syncthreads();
    if (edge) { fixup<2>(A, tid, y0, x0); __syncthreads(); }
    do_update<1>(B, A, rq, cp, skel, oth, OT, base, x0, y0, PH1, d0, d1, d2, a0, a1);
    __syncthreads();

    erode2<3>(A, B, tid);
    __syncthreads();
    if (edge) { fixup<3>(B, tid, y0, x0); __syncthreads(); }
    do_update<1>(A, B, rq, cp, skel, oth, OT, base, x0, y0, PH1, d0, d1, d2, a0, a1);
    __syncthreads();

    erode2<4>(B, A, tid);
    __syncthreads();
    if (edge) { fixup<4>(A, tid, y0, x0); __syncthreads(); }
    do_update<2>(B, A, rq, cp, skel, oth, OT, base, x0, y0, PH1, d0, d1, d2, a0, a1);

    // ---- block reduction: wave shuffle -> LDS -> spread atomics
    int wave = tid >> 6, lane = tid & 63;
    for (int o = 32; o > 0; o >>= 1) {
        a0 += __shfl_down(a0, o, 64);
        a1 += __shfl_down(a1, o, 64);
    }
    if (lane == 0) { sh[wave] = a0; sh[8 + wave] = a1; }
    if (PH1) {
        for (int o = 32; o > 0; o >>= 1) {
            d0 += __shfl_down(d0, o, 64);
            d1 += __shfl_down(d1, o, 64);
            d2 += __shfl_down(d2, o, 64);
        }
        if (lane == 0) { sh[16 + wave] = d0; sh[24 + wave] = d1; sh[32 + wave] = d2; }
    }
    __syncthreads();
    if (tid == 0) {
        float s0 = 0.f, s1 = 0.f;
        for (int wv = 0; wv < 8; wv++) { s0 += sh[wv]; s1 += sh[8 + wv]; }
        int lb = blockIdx.x + GRID_X * blockIdx.y;
        int slot = (lb + blockIdx.z * 37) & (PSLOTS - 1);
        atomicAdd(&accP[slot * 32 + (PH1 ? 0 : 2)], s0);
        atomicAdd(&accP[slot * 32 + (PH1 ? 1 : 3)], s1);
        if (PH1) {
            float t0 = 0.f, t1 = 0.f, t2 = 0.f;
            for (int wv = 0; wv < 8; wv++) {
                t0 += sh[16 + wv]; t1 += sh[24 + wv]; t2 += sh[32 + wv];
            }
            float* dst = accD + (size_t)(img * DSLOTS + (lb & (DSLOTS - 1))) * 32;
            atomicAdd(&dst[0], t0);
            atomicAdd(&dst[1], t1);
            atomicAdd(&dst[2], t2);
        }
    }
}

__global__ __launch_bounds__(256) void final_combine(
        const float* __restrict__ accP,
        const float* __restrict__ accD,
        float* __restrict__ out) {
    __shared__ float shp[2][4];
    __shared__ float shd[NIMG][3];
    int tid = threadIdx.x;
    int lane = tid & 63, wave = tid >> 6;

    float p0 = 0.f, p1 = 0.f, p2 = 0.f, p3 = 0.f;
    if (tid < PSLOTS) {
        const float* s = accP + tid * 32;
        p0 = s[0]; p1 = s[1]; p2 = s[2]; p3 = s[3];
    }
    for (int o = 32; o > 0; o >>= 1) {
        p0 += __shfl_down(p0, o, 64); p1 += __shfl_down(p1, o, 64);
        p2 += __shfl_down(p2, o, 64); p3 += __shfl_down(p3, o, 64);
    }
    if (lane == 0 && wave < 2) {
        shp[wave][0] = p0; shp[wave][1] = p1; shp[wave][2] = p2; shp[wave][3] = p3;
    }

    int n = tid >> 4, s16 = tid & 15;
    const float* d = accD + (size_t)(n * DSLOTS + s16) * 32;
    float q0 = d[0], q1 = d[1], q2 = d[2];
    for (int o = 8; o > 0; o >>= 1) {
        q0 += __shfl_down(q0, o, 16);
        q1 += __shfl_down(q1, o, 16);
        q2 += __shfl_down(q2, o, 16);
    }
    if (s16 == 0) { shd[n][0] = q0; shd[n][1] = q1; shd[n][2] = q2; }
    __syncthreads();

    if (tid == 0) {
        float sumP  = shp[0][0] + shp[1][0];
        float sumPt = shp[0][1] + shp[1][1];
        float sumT  = shp[0][2] + shp[1][2];
        float sumTp = shp[0][3] + shp[1][3];
        const float SMOOTH = 1.0f;
        float tprec = (sumPt + SMOOTH) / (sumP + SMOOTH);
        float tsens = (sumTp + SMOOTH) / (sumT + SMOOTH);
        float cl = 1.0f - 2.0f * (tprec * tsens) / (tprec + tsens);
        const float EPS = 1e-4f;
        float dsum = 0.f;
        for (int k = 0; k < NIMG; k++) {
            float gd = (2.0f * shd[k][0] + EPS) / (shd[k][1] + shd[k][2] + EPS);
            dsum += 1.0f - gd;
        }
        out[0] = 0.5f * cl + 0.5f * (dsum / (float)NIMG);
    }
}

extern "C" void kernel_launch(void* const* d_in, const int* in_sizes, int n_in,
                              void* d_out, int out_size, void* d_ws, size_t ws_size,
                              hipStream_t stream) {
    const float* y_pred = (const float*)d_in[0];
    const float* y_true = (const float*)d_in[1];
    float* out = (float*)d_out;

    float* accP = (float*)d_ws;                  // 128*32 floats
    float* accD = accP + PSLOTS * 32;            // 16*16*32 floats

    hipMemsetAsync(accP, 0, (PSLOTS * 32 + NIMG * DSLOTS * 32) * sizeof(float),
                   stream);

    dim3 grd(GRID_X, GRID_Y, 2 * NIMG), blk(BLKT);   // 8192 blocks, both phases
    cl_fused<<<grd, blk, 0, stream>>>(y_pred, y_true, accP, accD);
    final_combine<<<1, 256, 0, stream>>>(accP, accD, out);
}

// Round 7
// 316.250 us; speedup vs baseline: 1.2299x; 1.2280x over previous
//
#include <hip/hip_runtime.h>
#include <math.h>

// clDice loss: 16 x 1 x 1024 x 1024 fp32 inputs, scalar fp32 output.
// Round 7: barrier-free wave-autonomous ROW STREAMING. Each wave owns 64
// consecutive columns (54 valid + 5 halo each side) and streams a 128-row
// band, keeping the full cascade (X, e1..e3, dilate row-maxes, skel chain)
// in depth-4 circular register FIFOs (static indices via unroll-4).
// Horizontal neighbors via __shfl; NO LDS, NO __syncthreads.
// Edge semantics = value replication (== +/-inf pool padding), done by
// lane-clamped shfl (column edges, edge strips only) and wave-uniform
// substitution selects (row edges, first/last row-groups only).

#define HH 1024
#define WW 1024
#define NIMG 16
constexpr int IMG_ELEMS = HH * WW;
constexpr int VALID = 54;            // output cols per wave
constexpr int NSTRIP = 19;           // 19*54 = 1026 >= 1024
constexpr int NBAND = 8;
constexpr int ROWS_B = 128;
constexpr int NZP = 2 * NIMG;        // img x phase
constexpr int WAVES = NSTRIP * NBAND * NZP;   // 4864
constexpr int BLKT = 256;                      // 4 waves/block
constexpr int NBLK = WAVES / 4;                // 1216
constexpr int PSLOTS = 128;
constexpr int DSLOTS = 16;

// ---- fast math: A&S 7.1.26 erf (|eps|<=1.5e-7) with v_exp_f32 / v_rcp_f32
__device__ __forceinline__ float gelu_fast(float x) {
    float z = x * 0.70710678118654752440f;
    float az = fabsf(z);
    float t = __builtin_amdgcn_rcpf(fmaf(az, 0.3275911f, 1.0f));
    float e = __expf(-az * az);
    float p = fmaf(1.061405429f, t, -1.453152027f);
    p = fmaf(p, t, 1.421413741f);
    p = fmaf(p, t, -0.284496736f);
    p = fmaf(p, t, 0.254829592f);
    p = p * t;
    float E = fmaf(-p, e, 1.0f);
    float erf_s = copysignf(E, x);
    return 0.5f * x * (1.0f + erf_s);
}

__device__ __forceinline__ float sigmoid_fast(float x) {
    return __builtin_amdgcn_rcpf(1.0f + __expf(-x));
}

// One stream step at row r. Computes e1@r-1, e2@r-2, e3@r-3, e4@r-4 and
// skel updates 0..3 at rows r-2..r-5 respectively. RE = row-edge variant
// (substitution selects active), CE = column-edge strip (lane-clamp shfl
// replication after each erode level).
template <bool RE, bool CE>
__device__ __forceinline__ void step_one(
        int u, int r,
        const float* __restrict__ X, const float* __restrict__ OT,
        size_t base, int colc, int srcLane, float cm, int rb, bool PH1,
        float (&x)[4], float (&e1)[4], float (&e2)[4], float (&e3)[4],
        float (&hm1)[4], float (&hm2)[4], float (&hm3)[4], float (&hm4)[4],
        float (&sk0)[4], float (&sk1)[4], float (&sk2)[4], float (&oth)[4],
        float (&px)[2], float (&pt)[2],
        float& a0, float& a1, float& d0, float& d1, float& d2) {
    const int I0 = (u + 3) & 3, I1 = (u + 2) & 3, I2 = (u + 1) & 3, I3 = u & 3;
    const int IA = (u + 1) & 1;     // == r & 1

    // prefetched X row r; issue load for row r+2
    float xv = px[IA];
    {
        int rc = min(max(r + 2, 0), HH - 1);
        px[IA] = X[base + (size_t)rc * WW + colc];
    }
    x[I0] = xv;
    // prefetched OT row r-2; issue load for row r
    float tv = pt[IA];
    {
        int rc = min(max(r, 0), HH - 1);
        pt[IA] = OT[base + (size_t)rc * WW + colc];
    }

    // ---- e1 @ r-1 (X rows r-2..r; X row-clamp via loads is exact)
    float c1 = x[I1];
    float v1 = fminf(x[I2], xv);
    float e1v = fminf(fminf(v1, c1),
                      fminf(__shfl_up(c1, 1, 64), __shfl_down(c1, 1, 64)));
    if (CE) e1v = __shfl(e1v, srcLane, 64);
    e1[I1] = e1v;
    hm1[I1] = fmaxf(fmaxf(__shfl_up(e1v, 1, 64), e1v), __shfl_down(e1v, 1, 64));

    // ---- e2 @ r-2 (e1 rows r-3 [I3], r-2 [I2], r-1 [new])
    float c2 = e1[I2];
    float up2 = (RE && r < 3) ? c2 : e1[I3];
    float dn2 = (RE && r > 1024) ? c2 : e1v;
    float e2v = fminf(fminf(fminf(up2, dn2), c2),
                      fminf(__shfl_up(c2, 1, 64), __shfl_down(c2, 1, 64)));
    if (CE) e2v = __shfl(e2v, srcLane, 64);
    e2[I2] = e2v;
    hm2[I2] = fmaxf(fmaxf(__shfl_up(e2v, 1, 64), e2v), __shfl_down(e2v, 1, 64));

    // ---- e3 @ r-3 (e2 rows r-4 [I0], r-3 [I3], r-2 [new])
    float c3 = e2[I3];
    float up3 = (RE && r < 4) ? c3 : e2[I0];
    float dn3 = (RE && r > 1025) ? c3 : e2v;
    float e3v = fminf(fminf(fminf(up3, dn3), c3),
                      fminf(__shfl_up(c3, 1, 64), __shfl_down(c3, 1, 64)));
    if (CE) e3v = __shfl(e3v, srcLane, 64);
    e3[I3] = e3v;
    hm3[I3] = fmaxf(fmaxf(__shfl_up(e3v, 1, 64), e3v), __shfl_down(e3v, 1, 64));

    // ---- e4 @ r-4 (e3 rows r-5 [I1], r-4 [I0], r-3 [new])
    float c4 = e3[I0];
    float up4 = (RE && r < 5) ? c4 : e3[I1];
    float dn4 = (RE && r > 1026) ? c4 : e3v;
    float e4v = fminf(fminf(fminf(up4, dn4), c4),
                      fminf(__shfl_up(c4, 1, 64), __shfl_down(c4, 1, 64)));
    if (CE) e4v = __shfl(e4v, srcLane, 64);
    hm4[I0] = fmaxf(fmaxf(__shfl_up(e4v, 1, 64), e4v), __shfl_down(e4v, 1, 64));

    // ---- update0 @ r-2: skel0 = gelu(X - dil(e1)); stash other; dice
    float d1u = (RE && r < 3) ? hm1[I2] : hm1[I3];
    float d1d = (RE && r > 1024) ? hm1[I2] : hm1[I1];
    float dil1 = fmaxf(fmaxf(d1u, hm1[I2]), d1d);
    float p0 = x[I2];
    sk0[I2] = gelu_fast(p0 - dil1);
    oth[I2] = tv;
    if (PH1 && (unsigned)(r - 2 - rb) < (unsigned)ROWS_B) {
        float pv = sigmoid_fast(p0);
        float pvm = pv * cm;
        d0 = fmaf(pvm, tv, d0);
        d1 += pvm;
        d2 = fmaf(tv, cm, d2);
    }

    // ---- update1 @ r-3 (hm2 rows r-4 [I0], r-3 [I3], r-2 [I2])
    float d2u = (RE && r < 4) ? hm2[I3] : hm2[I0];
    float d2d = (RE && r > 1025) ? hm2[I3] : hm2[I2];
    float dil2 = fmaxf(fmaxf(d2u, hm2[I3]), d2d);
    float dlt1 = gelu_fast(e1[I3] - dil2);
    float s0v = sk0[I3];
    sk1[I3] = s0v + gelu_fast(fmaf(-s0v, dlt1, dlt1));

    // ---- update2 @ r-4 (hm3 rows r-5 [I1], r-4 [I0], r-3 [I3])
    float d3u = (RE && r < 5) ? hm3[I0] : hm3[I1];
    float d3d = (RE && r > 1026) ? hm3[I0] : hm3[I3];
    float dil3 = fmaxf(fmaxf(d3u, hm3[I0]), d3d);
    float dlt2 = gelu_fast(e2[I0] - dil3);
    float s1v = sk1[I0];
    sk2[I0] = s1v + gelu_fast(fmaf(-s1v, dlt2, dlt2));

    // ---- update3 @ r-5 (hm4 rows r-6 [I2], r-5 [I1], r-4 [I0])
    float d4u = (RE && r < 6) ? hm4[I1] : hm4[I2];
    float d4d = (RE && r > 1027) ? hm4[I1] : hm4[I0];
    float dil4 = fmaxf(fmaxf(d4u, hm4[I1]), d4d);
    float dlt3 = gelu_fast(e3[I1] - dil4);
    float s2v = sk2[I1];
    float sfin = s2v + gelu_fast(fmaf(-s2v, dlt3, dlt3));
    if ((unsigned)(r - 5 - rb) < (unsigned)ROWS_B) {
        float sm = sfin * cm;
        a0 += sm;
        a1 = fmaf(sm, oth[I1], a1);
    }
}

template <bool CE>
__device__ __forceinline__ void run_band(
        const float* __restrict__ X, const float* __restrict__ OT,
        size_t base, int colc, int srcLane, float cm, int rb, bool PH1,
        float& a0, float& a1, float& d0, float& d1, float& d2) {
    float x[4] = {0, 0, 0, 0}, e1[4] = {0, 0, 0, 0};
    float e2[4] = {0, 0, 0, 0}, e3[4] = {0, 0, 0, 0};
    float hm1[4] = {0, 0, 0, 0}, hm2[4] = {0, 0, 0, 0};
    float hm3[4] = {0, 0, 0, 0}, hm4[4] = {0, 0, 0, 0};
    float sk0[4] = {0, 0, 0, 0}, sk1[4] = {0, 0, 0, 0};
    float sk2[4] = {0, 0, 0, 0}, oth[4] = {0, 0, 0, 0};
    float px[2], pt[2];

    const int r0 = rb - 5;   // rb even -> r0 odd
    {
        int rc = min(max(r0, 0), HH - 1);
        px[r0 & 1] = X[base + (size_t)rc * WW + colc];
        rc = min(max(r0 + 1, 0), HH - 1);
        px[(r0 + 1) & 1] = X[base + (size_t)rc * WW + colc];
        rc = min(max(r0 - 2, 0), HH - 1);
        pt[r0 & 1] = OT[base + (size_t)rc * WW + colc];
        rc = min(max(r0 - 1, 0), HH - 1);
        pt[(r0 + 1) & 1] = OT[base + (size_t)rc * WW + colc];
    }

    for (int g = 0; g < 35; g++) {           // 140 steps
        const int rg = r0 + g * 4;
        if (rg < 6 || rg > 1021) {
#pragma unroll
            for (int u = 0; u < 4; u++)
                step_one<true, CE>(u, rg + u, X, OT, base, colc, srcLane, cm,
                                   rb, PH1, x, e1, e2, e3, hm1, hm2, hm3, hm4,
                                   sk0, sk1, sk2, oth, px, pt, a0, a1, d0, d1, d2);
        } else {
#pragma unroll
            for (int u = 0; u < 4; u++)
                step_one<false, CE>(u, rg + u, X, OT, base, colc, srcLane, cm,
                                    rb, PH1, x, e1, e2, e3, hm1, hm2, hm3, hm4,
                                    sk0, sk1, sk2, oth, px, pt, a0, a1, d0, d1, d2);
        }
    }
}

// accP: PSLOTS cachelines of 32 floats: slot*32 + {0:sumP,1:sumP*t,2:sumT,3:sumT*p}
// accD: (img*DSLOTS + s)*32 + {0:inter, 1:sum sigmoid(p), 2:sum t}
__global__ __launch_bounds__(BLKT, 4) void cl_stream(
        const float* __restrict__ y_pred,
        const float* __restrict__ y_true,
        float* __restrict__ accP,
        float* __restrict__ accD) {
    const int wv = blockIdx.x * 4 + (threadIdx.x >> 6);
    const int lane = threadIdx.x & 63;
    int tmp = wv;
    const int strip = tmp % NSTRIP; tmp /= NSTRIP;
    const int band = tmp % NBAND;   tmp /= NBAND;
    const int img = tmp & (NIMG - 1);
    const bool PH1 = tmp < NIMG;
    const float* __restrict__ X  = PH1 ? y_pred : y_true;
    const float* __restrict__ OT = PH1 ? y_true : y_pred;
    const size_t base = (size_t)img * IMG_ELEMS;

    const int col = strip * VALID - 5 + lane;
    const int colc = min(max(col, 0), WW - 1);
    const float cm = (lane >= 5 && lane <= 58 && col < WW) ? 1.0f : 0.0f;
    const int rb = band * ROWS_B;

    const int loL = max(0, 5 - strip * VALID);
    const int hiL = min(63, (WW - 1) - (strip * VALID - 5));
    const int srcLane = min(max(lane, loL), hiL);
    const bool colEdge = (loL > 0) || (hiL < 63);

    float a0 = 0.f, a1 = 0.f, d0 = 0.f, d1 = 0.f, d2 = 0.f;
    if (colEdge)
        run_band<true >(X, OT, base, colc, srcLane, cm, rb, PH1, a0, a1, d0, d1, d2);
    else
        run_band<false>(X, OT, base, colc, srcLane, cm, rb, PH1, a0, a1, d0, d1, d2);

    // ---- wave reduce + spread atomics
    for (int o = 1; o < 64; o <<= 1) {
        a0 += __shfl_xor(a0, o, 64);
        a1 += __shfl_xor(a1, o, 64);
    }
    if (PH1) {
        for (int o = 1; o < 64; o <<= 1) {
            d0 += __shfl_xor(d0, o, 64);
            d1 += __shfl_xor(d1, o, 64);
            d2 += __shfl_xor(d2, o, 64);
        }
    }
    if (lane == 0) {
        int slot = (wv * 37) & (PSLOTS - 1);
        atomicAdd(&accP[slot * 32 + (PH1 ? 0 : 2)], a0);
        atomicAdd(&accP[slot * 32 + (PH1 ? 1 : 3)], a1);
        if (PH1) {
            int ds = (strip + band * 7) & (DSLOTS - 1);
            float* dst = accD + (size_t)(img * DSLOTS + ds) * 32;
            atomicAdd(&dst[0], d0);
            atomicAdd(&dst[1], d1);
            atomicAdd(&dst[2], d2);
        }
    }
}

__global__ __launch_bounds__(256) void final_combine(
        const float* __restrict__ accP,
        const float* __restrict__ accD,
        float* __restrict__ out) {
    __shared__ float shp[2][4];
    __shared__ float shd[NIMG][3];
    int tid = threadIdx.x;
    int lane = tid & 63, wave = tid >> 6;

    float p0 = 0.f, p1 = 0.f, p2 = 0.f, p3 = 0.f;
    if (tid < PSLOTS) {
        const float* s = accP + tid * 32;
        p0 = s[0]; p1 = s[1]; p2 = s[2]; p3 = s[3];
    }
    for (int o = 32; o > 0; o >>= 1) {
        p0 += __shfl_down(p0, o, 64); p1 += __shfl_down(p1, o, 64);
        p2 += __shfl_down(p2, o, 64); p3 += __shfl_down(p3, o, 64);
    }
    if (lane == 0 && wave < 2) {
        shp[wave][0] = p0; shp[wave][1] = p1; shp[wave][2] = p2; shp[wave][3] = p3;
    }

    int n = tid >> 4, s16 = tid & 15;
    const float* d = accD + (size_t)(n * DSLOTS + s16) * 32;
    float q0 = d[0], q1 = d[1], q2 = d[2];
    for (int o = 8; o > 0; o >>= 1) {
        q0 += __shfl_down(q0, o, 16);
        q1 += __shfl_down(q1, o, 16);
        q2 += __shfl_down(q2, o, 16);
    }
    if (s16 == 0) { shd[n][0] = q0; shd[n][1] = q1; shd[n][2] = q2; }
    __syncthreads();

    if (tid == 0) {
        float sumP  = shp[0][0] + shp[1][0];
        float sumPt = shp[0][1] + shp[1][1];
        float sumT  = shp[0][2] + shp[1][2];
        float sumTp = shp[0][3] + shp[1][3];
        const float SMOOTH = 1.0f;
        float tprec = (sumPt + SMOOTH) / (sumP + SMOOTH);
        float tsens = (sumTp + SMOOTH) / (sumT + SMOOTH);
        float cl = 1.0f - 2.0f * (tprec * tsens) / (tprec + tsens);
        const float EPS = 1e-4f;
        float dsum = 0.f;
        for (int k = 0; k < NIMG; k++) {
            float gd = (2.0f * shd[k][0] + EPS) / (shd[k][1] + shd[k][2] + EPS);
            dsum += 1.0f - gd;
        }
        out[0] = 0.5f * cl + 0.5f * (dsum / (float)NIMG);
    }
}

extern "C" void kernel_launch(void* const* d_in, const int* in_sizes, int n_in,
                              void* d_out, int out_size, void* d_ws, size_t ws_size,
                              hipStream_t stream) {
    const float* y_pred = (const float*)d_in[0];
    const float* y_true = (const float*)d_in[1];
    float* out = (float*)d_out;

    float* accP = (float*)d_ws;                  // 128*32 floats
    float* accD = accP + PSLOTS * 32;            // 16*16*32 floats

    hipMemsetAsync(accP, 0, (PSLOTS * 32 + NIMG * DSLOTS * 32) * sizeof(float),
                   stream);

    cl_stream<<<NBLK, BLKT, 0, stream>>>(y_pred, y_true, accP, accD);
    final_combine<<<1, 256, 0, stream>>>(accP, accD, out);
}

// Round 8
// 261.587 us; speedup vs baseline: 1.4869x; 1.2090x over previous
//
#include <hip/hip_runtime.h>
#include <math.h>

// clDice loss: 16 x 1 x 1024 x 1024 fp32 inputs, scalar fp32 output.
// Round 8 = Round 7 structure (barrier-free wave-autonomous row streaming,
// register FIFOs, shfl neighbors, no LDS/no syncthreads) with the GELU
// swapped for the Bowling logistic approximation of the normal CDF:
//   Phi(x) ~= sigmoid(1.5976x + 0.070565992x^3), |err| <= 1.4e-4
// log2(e) folded into the cubic so v_exp_f32 (exp2) is used directly:
// 5 VALU + 2 trans per GELU vs 14 VALU + 2 trans for A&S erf.

#define HH 1024
#define WW 1024
#define NIMG 16
constexpr int IMG_ELEMS = HH * WW;
constexpr int VALID = 54;            // output cols per wave
constexpr int NSTRIP = 19;           // 19*54 = 1026 >= 1024
constexpr int NBAND = 8;
constexpr int ROWS_B = 128;
constexpr int NZP = 2 * NIMG;        // img x phase
constexpr int WAVES = NSTRIP * NBAND * NZP;   // 4864
constexpr int BLKT = 256;                      // 4 waves/block
constexpr int NBLK = WAVES / 4;                // 1216
constexpr int PSLOTS = 128;
constexpr int DSLOTS = 16;

// ---- Bowling logistic CDF gelu: gelu(x) = x * sigmoid(1.5976x + 0.0706x^3)
// Coefficients pre-multiplied by -log2(e) for raw v_exp_f32 (exp2):
//   -1.5976*1.442695 = -2.3048494,  -0.070565992*1.442695 = -0.10180539
__device__ __forceinline__ float gelu_fast(float x) {
    float u = x * x;
    float w = x * fmaf(u, -0.10180539f, -2.3048494f);
    float e = __builtin_amdgcn_exp2f(w);
    return x * __builtin_amdgcn_rcpf(1.0f + e);
}

__device__ __forceinline__ float sigmoid_fast(float x) {
    float e = __builtin_amdgcn_exp2f(x * -1.442695041f);
    return __builtin_amdgcn_rcpf(1.0f + e);
}

// One stream step at row r. Computes e1@r-1, e2@r-2, e3@r-3, e4@r-4 and
// skel updates 0..3 at rows r-2..r-5 respectively. RE = row-edge variant
// (substitution selects active), CE = column-edge strip (lane-clamp shfl
// replication after each erode level).
template <bool RE, bool CE>
__device__ __forceinline__ void step_one(
        int u, int r,
        const float* __restrict__ X, const float* __restrict__ OT,
        size_t base, int colc, int srcLane, float cm, int rb, bool PH1,
        float (&x)[4], float (&e1)[4], float (&e2)[4], float (&e3)[4],
        float (&hm1)[4], float (&hm2)[4], float (&hm3)[4], float (&hm4)[4],
        float (&sk0)[4], float (&sk1)[4], float (&sk2)[4], float (&oth)[4],
        float (&px)[2], float (&pt)[2],
        float& a0, float& a1, float& d0, float& d1, float& d2) {
    const int I0 = (u + 3) & 3, I1 = (u + 2) & 3, I2 = (u + 1) & 3, I3 = u & 3;
    const int IA = (u + 1) & 1;     // == r & 1

    // prefetched X row r; issue load for row r+2
    float xv = px[IA];
    {
        int rc = min(max(r + 2, 0), HH - 1);
        px[IA] = X[base + (size_t)rc * WW + colc];
    }
    x[I0] = xv;
    // prefetched OT row r-2; issue load for row r
    float tv = pt[IA];
    {
        int rc = min(max(r, 0), HH - 1);
        pt[IA] = OT[base + (size_t)rc * WW + colc];
    }

    // ---- e1 @ r-1 (X rows r-2..r; X row-clamp via loads is exact)
    float c1 = x[I1];
    float v1 = fminf(x[I2], xv);
    float e1v = fminf(fminf(v1, c1),
                      fminf(__shfl_up(c1, 1, 64), __shfl_down(c1, 1, 64)));
    if (CE) e1v = __shfl(e1v, srcLane, 64);
    e1[I1] = e1v;
    hm1[I1] = fmaxf(fmaxf(__shfl_up(e1v, 1, 64), e1v), __shfl_down(e1v, 1, 64));

    // ---- e2 @ r-2 (e1 rows r-3 [I3], r-2 [I2], r-1 [new])
    float c2 = e1[I2];
    float up2 = (RE && r < 3) ? c2 : e1[I3];
    float dn2 = (RE && r > 1024) ? c2 : e1v;
    float e2v = fminf(fminf(fminf(up2, dn2), c2),
                      fminf(__shfl_up(c2, 1, 64), __shfl_down(c2, 1, 64)));
    if (CE) e2v = __shfl(e2v, srcLane, 64);
    e2[I2] = e2v;
    hm2[I2] = fmaxf(fmaxf(__shfl_up(e2v, 1, 64), e2v), __shfl_down(e2v, 1, 64));

    // ---- e3 @ r-3 (e2 rows r-4 [I0], r-3 [I3], r-2 [new])
    float c3 = e2[I3];
    float up3 = (RE && r < 4) ? c3 : e2[I0];
    float dn3 = (RE && r > 1025) ? c3 : e2v;
    float e3v = fminf(fminf(fminf(up3, dn3), c3),
                      fminf(__shfl_up(c3, 1, 64), __shfl_down(c3, 1, 64)));
    if (CE) e3v = __shfl(e3v, srcLane, 64);
    e3[I3] = e3v;
    hm3[I3] = fmaxf(fmaxf(__shfl_up(e3v, 1, 64), e3v), __shfl_down(e3v, 1, 64));

    // ---- e4 @ r-4 (e3 rows r-5 [I1], r-4 [I0], r-3 [new])
    float c4 = e3[I0];
    float up4 = (RE && r < 5) ? c4 : e3[I1];
    float dn4 = (RE && r > 1026) ? c4 : e3v;
    float e4v = fminf(fminf(fminf(up4, dn4), c4),
                      fminf(__shfl_up(c4, 1, 64), __shfl_down(c4, 1, 64)));
    if (CE) e4v = __shfl(e4v, srcLane, 64);
    hm4[I0] = fmaxf(fmaxf(__shfl_up(e4v, 1, 64), e4v), __shfl_down(e4v, 1, 64));

    // ---- update0 @ r-2: skel0 = gelu(X - dil(e1)); stash other; dice
    float d1u = (RE && r < 3) ? hm1[I2] : hm1[I3];
    float d1d = (RE && r > 1024) ? hm1[I2] : hm1[I1];
    float dil1 = fmaxf(fmaxf(d1u, hm1[I2]), d1d);
    float p0 = x[I2];
    sk0[I2] = gelu_fast(p0 - dil1);
    oth[I2] = tv;
    if (PH1 && (unsigned)(r - 2 - rb) < (unsigned)ROWS_B) {
        float pv = sigmoid_fast(p0);
        float pvm = pv * cm;
        d0 = fmaf(pvm, tv, d0);
        d1 += pvm;
        d2 = fmaf(tv, cm, d2);
    }

    // ---- update1 @ r-3 (hm2 rows r-4 [I0], r-3 [I3], r-2 [I2])
    float d2u = (RE && r < 4) ? hm2[I3] : hm2[I0];
    float d2d = (RE && r > 1025) ? hm2[I3] : hm2[I2];
    float dil2 = fmaxf(fmaxf(d2u, hm2[I3]), d2d);
    float dlt1 = gelu_fast(e1[I3] - dil2);
    float s0v = sk0[I3];
    sk1[I3] = s0v + gelu_fast(fmaf(-s0v, dlt1, dlt1));

    // ---- update2 @ r-4 (hm3 rows r-5 [I1], r-4 [I0], r-3 [I3])
    float d3u = (RE && r < 5) ? hm3[I0] : hm3[I1];
    float d3d = (RE && r > 1026) ? hm3[I0] : hm3[I3];
    float dil3 = fmaxf(fmaxf(d3u, hm3[I0]), d3d);
    float dlt2 = gelu_fast(e2[I0] - dil3);
    float s1v = sk1[I0];
    sk2[I0] = s1v + gelu_fast(fmaf(-s1v, dlt2, dlt2));

    // ---- update3 @ r-5 (hm4 rows r-6 [I2], r-5 [I1], r-4 [I0])
    float d4u = (RE && r < 6) ? hm4[I1] : hm4[I2];
    float d4d = (RE && r > 1027) ? hm4[I1] : hm4[I0];
    float dil4 = fmaxf(fmaxf(d4u, hm4[I1]), d4d);
    float dlt3 = gelu_fast(e3[I1] - dil4);
    float s2v = sk2[I1];
    float sfin = s2v + gelu_fast(fmaf(-s2v, dlt3, dlt3));
    if ((unsigned)(r - 5 - rb) < (unsigned)ROWS_B) {
        float sm = sfin * cm;
        a0 += sm;
        a1 = fmaf(sm, oth[I1], a1);
    }
}

template <bool CE>
__device__ __forceinline__ void run_band(
        const float* __restrict__ X, const float* __restrict__ OT,
        size_t base, int colc, int srcLane, float cm, int rb, bool PH1,
        float& a0, float& a1, float& d0, float& d1, float& d2) {
    float x[4] = {0, 0, 0, 0}, e1[4] = {0, 0, 0, 0};
    float e2[4] = {0, 0, 0, 0}, e3[4] = {0, 0, 0, 0};
    float hm1[4] = {0, 0, 0, 0}, hm2[4] = {0, 0, 0, 0};
    float hm3[4] = {0, 0, 0, 0}, hm4[4] = {0, 0, 0, 0};
    float sk0[4] = {0, 0, 0, 0}, sk1[4] = {0, 0, 0, 0};
    float sk2[4] = {0, 0, 0, 0}, oth[4] = {0, 0, 0, 0};
    float px[2], pt[2];

    const int r0 = rb - 5;   // rb even -> r0 odd
    {
        int rc = min(max(r0, 0), HH - 1);
        px[r0 & 1] = X[base + (size_t)rc * WW + colc];
        rc = min(max(r0 + 1, 0), HH - 1);
        px[(r0 + 1) & 1] = X[base + (size_t)rc * WW + colc];
        rc = min(max(r0 - 2, 0), HH - 1);
        pt[r0 & 1] = OT[base + (size_t)rc * WW + colc];
        rc = min(max(r0 - 1, 0), HH - 1);
        pt[(r0 + 1) & 1] = OT[base + (size_t)rc * WW + colc];
    }

    for (int g = 0; g < 35; g++) {           // 140 steps
        const int rg = r0 + g * 4;
        if (rg < 6 || rg > 1021) {
#pragma unroll
            for (int u = 0; u < 4; u++)
                step_one<true, CE>(u, rg + u, X, OT, base, colc, srcLane, cm,
                                   rb, PH1, x, e1, e2, e3, hm1, hm2, hm3, hm4,
                                   sk0, sk1, sk2, oth, px, pt, a0, a1, d0, d1, d2);
        } else {
#pragma unroll
            for (int u = 0; u < 4; u++)
                step_one<false, CE>(u, rg + u, X, OT, base, colc, srcLane, cm,
                                    rb, PH1, x, e1, e2, e3, hm1, hm2, hm3, hm4,
                                    sk0, sk1, sk2, oth, px, pt, a0, a1, d0, d1, d2);
        }
    }
}

// accP: PSLOTS cachelines of 32 floats: slot*32 + {0:sumP,1:sumP*t,2:sumT,3:sumT*p}
// accD: (img*DSLOTS + s)*32 + {0:inter, 1:sum sigmoid(p), 2:sum t}
__global__ __launch_bounds__(BLKT, 4) void cl_stream(
        const float* __restrict__ y_pred,
        const float* __restrict__ y_true,
        float* __restrict__ accP,
        float* __restrict__ accD) {
    const int wv = blockIdx.x * 4 + (threadIdx.x >> 6);
    const int lane = threadIdx.x & 63;
    int tmp = wv;
    const int strip = tmp % NSTRIP; tmp /= NSTRIP;
    const int band = tmp % NBAND;   tmp /= NBAND;
    const int img = tmp & (NIMG - 1);
    const bool PH1 = tmp < NIMG;
    const float* __restrict__ X  = PH1 ? y_pred : y_true;
    const float* __restrict__ OT = PH1 ? y_true : y_pred;
    const size_t base = (size_t)img * IMG_ELEMS;

    const int col = strip * VALID - 5 + lane;
    const int colc = min(max(col, 0), WW - 1);
    const float cm = (lane >= 5 && lane <= 58 && col < WW) ? 1.0f : 0.0f;
    const int rb = band * ROWS_B;

    const int loL = max(0, 5 - strip * VALID);
    const int hiL = min(63, (WW - 1) - (strip * VALID - 5));
    const int srcLane = min(max(lane, loL), hiL);
    const bool colEdge = (loL > 0) || (hiL < 63);

    float a0 = 0.f, a1 = 0.f, d0 = 0.f, d1 = 0.f, d2 = 0.f;
    if (colEdge)
        run_band<true >(X, OT, base, colc, srcLane, cm, rb, PH1, a0, a1, d0, d1, d2);
    else
        run_band<false>(X, OT, base, colc, srcLane, cm, rb, PH1, a0, a1, d0, d1, d2);

    // ---- wave reduce + spread atomics
    for (int o = 1; o < 64; o <<= 1) {
        a0 += __shfl_xor(a0, o, 64);
        a1 += __shfl_xor(a1, o, 64);
    }
    if (PH1) {
        for (int o = 1; o < 64; o <<= 1) {
            d0 += __shfl_xor(d0, o, 64);
            d1 += __shfl_xor(d1, o, 64);
            d2 += __shfl_xor(d2, o, 64);
        }
    }
    if (lane == 0) {
        int slot = (wv * 37) & (PSLOTS - 1);
        atomicAdd(&accP[slot * 32 + (PH1 ? 0 : 2)], a0);
        atomicAdd(&accP[slot * 32 + (PH1 ? 1 : 3)], a1);
        if (PH1) {
            int ds = (strip + band * 7) & (DSLOTS - 1);
            float* dst = accD + (size_t)(img * DSLOTS + ds) * 32;
            atomicAdd(&dst[0], d0);
            atomicAdd(&dst[1], d1);
            atomicAdd(&dst[2], d2);
        }
    }
}

__global__ __launch_bounds__(256) void final_combine(
        const float* __restrict__ accP,
        const float* __restrict__ accD,
        float* __restrict__ out) {
    __shared__ float shp[2][4];
    __shared__ float shd[NIMG][3];
    int tid = threadIdx.x;
    int lane = tid & 63, wave = tid >> 6;

    float p0 = 0.f, p1 = 0.f, p2 = 0.f, p3 = 0.f;
    if (tid < PSLOTS) {
        const float* s = accP + tid * 32;
        p0 = s[0]; p1 = s[1]; p2 = s[2]; p3 = s[3];
    }
    for (int o = 32; o > 0; o >>= 1) {
        p0 += __shfl_down(p0, o, 64); p1 += __shfl_down(p1, o, 64);
        p2 += __shfl_down(p2, o, 64); p3 += __shfl_down(p3, o, 64);
    }
    if (lane == 0 && wave < 2) {
        shp[wave][0] = p0; shp[wave][1] = p1; shp[wave][2] = p2; shp[wave][3] = p3;
    }

    int n = tid >> 4, s16 = tid & 15;
    const float* d = accD + (size_t)(n * DSLOTS + s16) * 32;
    float q0 = d[0], q1 = d[1], q2 = d[2];
    for (int o = 8; o > 0; o >>= 1) {
        q0 += __shfl_down(q0, o, 16);
        q1 += __shfl_down(q1, o, 16);
        q2 += __shfl_down(q2, o, 16);
    }
    if (s16 == 0) { shd[n][0] = q0; shd[n][1] = q1; shd[n][2] = q2; }
    __syncthreads();

    if (tid == 0) {
        float sumP  = shp[0][0] + shp[1][0];
        float sumPt = shp[0][1] + shp[1][1];
        float sumT  = shp[0][2] + shp[1][2];
        float sumTp = shp[0][3] + shp[1][3];
        const float SMOOTH = 1.0f;
        float tprec = (sumPt + SMOOTH) / (sumP + SMOOTH);
        float tsens = (sumTp + SMOOTH) / (sumT + SMOOTH);
        float cl = 1.0f - 2.0f * (tprec * tsens) / (tprec + tsens);
        const float EPS = 1e-4f;
        float dsum = 0.f;
        for (int k = 0; k < NIMG; k++) {
            float gd = (2.0f * shd[k][0] + EPS) / (shd[k][1] + shd[k][2] + EPS);
            dsum += 1.0f - gd;
        }
        out[0] = 0.5f * cl + 0.5f * (dsum / (float)NIMG);
    }
}

extern "C" void kernel_launch(void* const* d_in, const int* in_sizes, int n_in,
                              void* d_out, int out_size, void* d_ws, size_t ws_size,
                              hipStream_t stream) {
    const float* y_pred = (const float*)d_in[0];
    const float* y_true = (const float*)d_in[1];
    float* out = (float*)d_out;

    float* accP = (float*)d_ws;                  // 128*32 floats
    float* accD = accP + PSLOTS * 32;            // 16*16*32 floats

    hipMemsetAsync(accP, 0, (PSLOTS * 32 + NIMG * DSLOTS * 32) * sizeof(float),
                   stream);

    cl_stream<<<NBLK, BLKT, 0, stream>>>(y_pred, y_true, accP, accD);
    final_combine<<<1, 256, 0, stream>>>(accP, accD, out);
}